// Round 4
// baseline (16346.750 us; speedup 1.0000x reference)
//
#include <hip/hip_runtime.h>
#include <utility>
#include <cstddef>

// ---------------- compile-time Ivanic-Ruedenberg tables ----------------

struct Term { int o; int r; int a; float c; };
struct LTable { int n; Term t[1024]; };

constexpr double csqrt(double x) {
    if (x <= 0.0) return 0.0;
    double g = x < 1.0 ? 1.0 : x;
    for (int i = 0; i < 50; ++i) g = 0.5 * (g + x / g);
    return g;
}
constexpr int cabs_i(int x) { return x < 0 ? -x : x; }
constexpr int cmax_i(int a, int b) { return a > b ? a : b; }

constexpr void add_p(LTable& T, int o, double scale, int i, int a, int b, int l) {
    int lp = l - 1;
    int np = 2 * lp + 1;
    int row = i + 1;
    if (b == l) {
        T.t[T.n++] = Term{o, row * 3 + 2, (a + lp) * np + 2 * lp, (float)scale};
        T.t[T.n++] = Term{o, row * 3 + 0, (a + lp) * np + 0,      (float)(-scale)};
    } else if (b == -l) {
        T.t[T.n++] = Term{o, row * 3 + 2, (a + lp) * np + 0,      (float)scale};
        T.t[T.n++] = Term{o, row * 3 + 0, (a + lp) * np + 2 * lp, (float)scale};
    } else {
        T.t[T.n++] = Term{o, row * 3 + 1, (a + lp) * np + (b + lp), (float)scale};
    }
}

constexpr LTable ru_table(int l) {
    LTable T{};
    int n = 2 * l + 1;
    for (int m = -l; m <= l; ++m) {
        for (int mp = -l; mp <= l; ++mp) {
            double denom = (cabs_i(mp) == l) ? (double)((2 * l) * (2 * l - 1))
                                             : (double)((l + mp) * (l - mp));
            double d0 = (m == 0) ? 1.0 : 0.0;
            double u = csqrt((double)((l + m) * (l - m)) / denom);
            double v = 0.5 * csqrt((1.0 + d0) * (l + cabs_i(m) - 1) * (l + cabs_i(m)) / denom)
                       * (1.0 - 2.0 * d0);
            double w = -0.5 * csqrt((double)cmax_i(l - cabs_i(m) - 1, 0) * (l - cabs_i(m)) / denom)
                       * (1.0 - d0);
            int o = (m + l) * n + (mp + l);
            if (u != 0.0) add_p(T, o, u, 0, m, mp, l);
            if (v != 0.0) {
                if (m == 0) {
                    add_p(T, o, v, 1, 1, mp, l);
                    add_p(T, o, v, -1, -1, mp, l);
                } else if (m > 0) {
                    double s = (m == 1) ? csqrt(2.0) : 1.0;
                    add_p(T, o, v * s, 1, m - 1, mp, l);
                    if (m != 1) add_p(T, o, -v, -1, -m + 1, mp, l);
                } else {
                    if (m != -1) add_p(T, o, v, 1, m + 1, mp, l);
                    double s = (m == -1) ? csqrt(2.0) : 1.0;
                    add_p(T, o, v * s, -1, -m - 1, mp, l);
                }
            }
            if (w != 0.0) {
                if (m > 0) {
                    add_p(T, o, w, 1, m + 1, mp, l);
                    add_p(T, o, w, -1, -m - 1, mp, l);
                } else {
                    add_p(T, o, w, 1, m - 1, mp, l);
                    add_p(T, o, -w, -1, -m + 1, mp, l);
                }
            }
        }
    }
    return T;
}

inline constexpr LTable T2 = ru_table(2);
inline constexpr LTable T3 = ru_table(3);
inline constexpr LTable T4 = ru_table(4);

template<const LTable& T, size_t... I>
__device__ __forceinline__ void apply_terms(float* __restrict__ D,
                                            const float* __restrict__ R1,
                                            const float* __restrict__ P,
                                            std::index_sequence<I...>) {
    ((D[T.t[I].o] += T.t[I].c * R1[T.t[I].r] * P[T.t[I].a]), ...);
}

// ---------------- output layout ----------------
// 25x25 block diagonal: blocks at offsets b*b with dim 2b+1, b=0..4

constexpr int blk_of(int x) { return x == 0 ? 0 : x < 4 ? 1 : x < 9 ? 2 : x < 16 ? 3 : 4; }
constexpr bool is_nz(int E) { return blk_of(E / 25) == blk_of(E % 25); }

constexpr int NNZ = 165;

// index of E among nonzero-structure positions (valid when is_nz(E))
constexpr int jof(int E) {
    int j = 0;
    for (int x = 0; x < E; ++x) if (is_nz(x)) ++j;
    return j;
}

struct PosTab { int p[NNZ]; };
constexpr PosTab make_pos() {
    PosTab P{};
    int j = 0;
    for (int E = 0; E < 625; ++E) if (is_nz(E)) P.p[j++] = E;
    return P;
}
__device__ constexpr PosTab POS = make_pos();

template<int E>
__device__ __forceinline__ float pick(const float* D1, const float* D2,
                                      const float* D3, const float* D4) {
    constexpr int r = E / 25, c = E % 25;
    constexpr int b = blk_of(r);
    static_assert(blk_of(c) == b, "pick only on block entries");
    constexpr int off = b * b, d = 2 * b + 1;
    constexpr int li = (r - off) * d + (c - off);
    if constexpr (b == 0) return 1.0f;
    else if constexpr (b == 1) return D1[li];
    else if constexpr (b == 2) return D2[li];
    else if constexpr (b == 3) return D3[li];
    else return D4[li];
}

// column-major compact store: ws[jof(E)*N + gp]
template<int E>
__device__ __forceinline__ void store_one(float* __restrict__ ws, int gp, int N,
                                          const float* D1, const float* D2,
                                          const float* D3, const float* D4) {
    if constexpr (is_nz(E)) {
        ws[(size_t)(jof(E)) * (size_t)N + (size_t)gp] = pick<E>(D1, D2, D3, D4);
    }
}

template<size_t... I>
__device__ __forceinline__ void store_all(float* __restrict__ ws, int gp, int N,
                                          const float* D1, const float* D2,
                                          const float* D3, const float* D4,
                                          std::index_sequence<I...>) {
    (store_one<(int)I>(ws, gp, N, D1, D2, D3, D4), ...);
}

// native clang vector type: required by __builtin_nontemporal_store
typedef float v4f __attribute__((ext_vector_type(4)));

// ---------------- kernel A: compute + compact column-major write ----------------

__global__ __launch_bounds__(256)
void wigner_compute_kernel(const float* __restrict__ xyz, float* __restrict__ ws, int Ntot) {
    const int gp = blockIdx.x * 256 + threadIdx.x;
    if (gp >= Ntot) return;

    const float x = xyz[3 * gp + 0];
    const float y = xyz[3 * gp + 1];
    const float z = xyz[3 * gp + 2];

    // angles without trig: ct = vz (clipped), st = sqrt(1-ct^2), cp/sp from x,y
    const float r2 = x * x + y * y + z * z;
    const float rinv = rsqrtf(fmaxf(r2, 1e-24f));
    const float ct = fminf(fmaxf(z * rinv, -1.0f), 1.0f);
    const float st = sqrtf(fmaxf(1.0f - ct * ct, 0.0f));
    const float rxy2 = x * x + y * y;
    float cp = 1.0f, sp = 0.0f;
    if (rxy2 > 0.0f) {
        const float ri = rsqrtf(rxy2);
        cp = x * ri;
        sp = y * ri;
    }

    // R1 in real-SH l=1 basis order (y,z,x), row-major 3x3
    float D1[9] = {cp,      0.0f, -sp,
                   st * sp, ct,   st * cp,
                   ct * sp, -st,  ct * cp};

    float D2[25] = {};
    apply_terms<T2>(D2, D1, D1, std::make_index_sequence<(size_t)T2.n>{});
    float D3[49] = {};
    apply_terms<T3>(D3, D1, D2, std::make_index_sequence<(size_t)T3.n>{});
    float D4[81] = {};
    apply_terms<T4>(D4, D1, D3, std::make_index_sequence<(size_t)T4.n>{});

    store_all(ws, gp, Ntot, D1, D2, D3, D4, std::make_index_sequence<625>{});
}

// ---------------- kernel B: expand compact records to full 625 rows ----------------
// Block: 256 threads, 256 points, 8 chunks of 32 points.
// LDS image 32x625 floats (80,000 B): structural zeros written once, nonzero
// slots overwritten per chunk from the compact records; flushed as contiguous
// 16B nontemporal v4f (chunk byte base = 32*2500*c, divisible by 16).
// Stage pattern: k = t + 256*i -> j = t/32 + 8*i, p0 = t&31; each 32-lane
// group reads one contiguous 128 B run of ws (two runs per wave-instr).
// LDS scatter bank = (17*p0 + pos[j]) % 32: permutation per group -> <=2-way.

__global__ __launch_bounds__(256, 2)
void wigner_expand_kernel(const float* __restrict__ ws, float* __restrict__ out, int Ntot) {
    __shared__ float img[32 * 625];
    __shared__ int spos[NNZ];

    const int t = threadIdx.x;
    if (t < NNZ) spos[t] = POS.p[t];

    // zero whole image once (zero-structure slots never rewritten)
    v4f* b4 = (v4f*)img;
    const v4f z4 = {0.0f, 0.0f, 0.0f, 0.0f};
#pragma unroll 4
    for (int k = t; k < 5000; k += 256) b4[k] = z4;
    __syncthreads();

    const int jbase = t >> 5;
    const int p0 = t & 31;
    const long long blk_f = (long long)blockIdx.x * 256 * 625;

    for (int c = 0; c < 8; ++c) {
        const int base_pt = blockIdx.x * 256 + c * 32;
        if (base_pt >= Ntot) break;  // uniform across block
        const int vp = min(32, Ntot - base_pt);

        // stage: gather compact records into the image
        if (p0 < vp) {
            const float* __restrict__ wp = ws + (size_t)jbase * (size_t)Ntot + base_pt + p0;
            float* __restrict__ row = img + p0 * 625;
#pragma unroll
            for (int i = 0; i < 21; ++i) {
                const int j = jbase + 8 * i;
                if (j < NNZ) {
                    row[spos[j]] = wp[(size_t)(8 * i) * (size_t)Ntot];
                }
            }
        }
        __syncthreads();

        const long long out_f = blk_f + (long long)c * 32 * 625;
        if (vp == 32) {
            const v4f* src = (const v4f*)img;
            v4f* dst = (v4f*)(out + out_f);
#pragma unroll 4
            for (int k = t; k < 5000; k += 256) {
                __builtin_nontemporal_store(src[k], dst + k);
            }
        } else {
            const int vf = vp * 625;
            for (int k = t; k < vf; k += 256) {
                out[out_f + k] = img[k];
            }
        }
        __syncthreads();
    }
}

extern "C" void kernel_launch(void* const* d_in, const int* in_sizes, int n_in,
                              void* d_out, int out_size, void* d_ws, size_t ws_size,
                              hipStream_t stream) {
    const float* xyz = (const float*)d_in[0];
    float* out = (float*)d_out;
    float* ws = (float*)d_ws;  // needs NNZ*N*4 = 132 MB; ws is ~2 GB
    const int N = in_sizes[0] / 3;
    const int blocks = (N + 255) / 256;
    hipLaunchKernelGGL(wigner_compute_kernel, dim3(blocks), dim3(256), 0, stream,
                       xyz, ws, N);
    hipLaunchKernelGGL(wigner_expand_kernel, dim3(blocks), dim3(256), 0, stream,
                       ws, out, N);
}

// Round 5
// 538.624 us; speedup vs baseline: 30.3491x; 30.3491x over previous
//
#include <hip/hip_runtime.h>
#include <utility>
#include <cstddef>

// ---------------- compile-time Ivanic-Ruedenberg tables ----------------

struct Term { int o; int r; int a; float c; };
struct LTable { int n; Term t[1024]; };

constexpr double csqrt(double x) {
    if (x <= 0.0) return 0.0;
    double g = x < 1.0 ? 1.0 : x;
    for (int i = 0; i < 50; ++i) g = 0.5 * (g + x / g);
    return g;
}
constexpr int cabs_i(int x) { return x < 0 ? -x : x; }
constexpr int cmax_i(int a, int b) { return a > b ? a : b; }

constexpr void add_p(LTable& T, int o, double scale, int i, int a, int b, int l) {
    int lp = l - 1;
    int np = 2 * lp + 1;
    int row = i + 1;
    if (b == l) {
        T.t[T.n++] = Term{o, row * 3 + 2, (a + lp) * np + 2 * lp, (float)scale};
        T.t[T.n++] = Term{o, row * 3 + 0, (a + lp) * np + 0,      (float)(-scale)};
    } else if (b == -l) {
        T.t[T.n++] = Term{o, row * 3 + 2, (a + lp) * np + 0,      (float)scale};
        T.t[T.n++] = Term{o, row * 3 + 0, (a + lp) * np + 2 * lp, (float)scale};
    } else {
        T.t[T.n++] = Term{o, row * 3 + 1, (a + lp) * np + (b + lp), (float)scale};
    }
}

constexpr LTable ru_table(int l) {
    LTable T{};
    int n = 2 * l + 1;
    for (int m = -l; m <= l; ++m) {
        for (int mp = -l; mp <= l; ++mp) {
            double denom = (cabs_i(mp) == l) ? (double)((2 * l) * (2 * l - 1))
                                             : (double)((l + mp) * (l - mp));
            double d0 = (m == 0) ? 1.0 : 0.0;
            double u = csqrt((double)((l + m) * (l - m)) / denom);
            double v = 0.5 * csqrt((1.0 + d0) * (l + cabs_i(m) - 1) * (l + cabs_i(m)) / denom)
                       * (1.0 - 2.0 * d0);
            double w = -0.5 * csqrt((double)cmax_i(l - cabs_i(m) - 1, 0) * (l - cabs_i(m)) / denom)
                       * (1.0 - d0);
            int o = (m + l) * n + (mp + l);
            if (u != 0.0) add_p(T, o, u, 0, m, mp, l);
            if (v != 0.0) {
                if (m == 0) {
                    add_p(T, o, v, 1, 1, mp, l);
                    add_p(T, o, v, -1, -1, mp, l);
                } else if (m > 0) {
                    double s = (m == 1) ? csqrt(2.0) : 1.0;
                    add_p(T, o, v * s, 1, m - 1, mp, l);
                    if (m != 1) add_p(T, o, -v, -1, -m + 1, mp, l);
                } else {
                    if (m != -1) add_p(T, o, v, 1, m + 1, mp, l);
                    double s = (m == -1) ? csqrt(2.0) : 1.0;
                    add_p(T, o, v * s, -1, -m - 1, mp, l);
                }
            }
            if (w != 0.0) {
                if (m > 0) {
                    add_p(T, o, w, 1, m + 1, mp, l);
                    add_p(T, o, w, -1, -m - 1, mp, l);
                } else {
                    add_p(T, o, w, 1, m - 1, mp, l);
                    add_p(T, o, -w, -1, -m + 1, mp, l);
                }
            }
        }
    }
    return T;
}

inline constexpr LTable T2 = ru_table(2);
inline constexpr LTable T3 = ru_table(3);
inline constexpr LTable T4 = ru_table(4);

// terms for a given output entry are contiguous by construction (m-major, mp-minor)
template<const LTable& T>
constexpr int er_start(int e) {
    for (int i = 0; i < T.n; ++i) if (T.t[i].o == e) return i;
    return 0;
}
template<const LTable& T>
constexpr int er_cnt(int e) {
    int c = 0;
    for (int i = 0; i < T.n; ++i) if (T.t[i].o == e) ++c;
    return c;
}

template<const LTable& T, int S, size_t... K>
__device__ __forceinline__ float sum_terms(const float* __restrict__ R1,
                                           const float* __restrict__ P,
                                           std::index_sequence<K...>) {
    float a = 0.0f;
    ((a = fmaf(T.t[S + (int)K].c, R1[T.t[S + (int)K].r] * P[T.t[S + (int)K].a], a)), ...);
    return a;
}

// compute one entry of block l, optionally keep in array, stream ds_write to row
template<const LTable& T, int l, bool KEEP, int e>
__device__ __forceinline__ void level_one(const float* __restrict__ R1,
                                          const float* __restrict__ P,
                                          float* __restrict__ keep,
                                          float* __restrict__ row) {
    constexpr int S = er_start<T>(e);
    constexpr int C = er_cnt<T>(e);
    float v = sum_terms<T, S>(R1, P, std::make_index_sequence<C>{});
    if constexpr (KEEP) keep[e] = v;
    constexpr int d = 2 * l + 1;
    constexpr int r = e / d, c = e % d;
    constexpr int E625 = (l * l + r) * 25 + (l * l + c);  // ds_write imm offset
    row[E625] = v;
}

template<const LTable& T, int l, bool KEEP, size_t... E>
__device__ __forceinline__ void level(const float* __restrict__ R1,
                                      const float* __restrict__ P,
                                      float* __restrict__ keep,
                                      float* __restrict__ row,
                                      std::index_sequence<E...>) {
    (level_one<T, l, KEEP, (int)E>(R1, P, keep, row), ...);
}

template<size_t... E>
__device__ __forceinline__ void write_l1(const float* __restrict__ D1,
                                         float* __restrict__ row,
                                         std::index_sequence<E...>) {
    ((row[(1 + (int)E / 3) * 25 + (1 + (int)E % 3)] = D1[E]), ...);
}

// native clang vector type: required by __builtin_nontemporal_store
typedef float v4f __attribute__((ext_vector_type(4)));

// ---------------- fused kernel ----------------
// Block: 256 threads = 256 points, 8 chunks of 32 points.
// LDS image 32x625 floats (80,000 B) -> 2 blocks/CU.
// Per chunk: the 32 owning threads RECOMPUTE their D from 4 live trig regs,
// streaming each entry into the image via compile-time-immediate ds_writes
// (one base register; bank = (17*p0+E)%32, permutation in p0 -> conflict-free).
// D4 is never materialized as an array: peak live floats = D1+D2+D3 = 83,
// so no scratch spills at the 128-VGPR cap of __launch_bounds__(256,2).
// Structural zeros written once at block start; l=0's 1.0 written per scatter.
// Copy phase: contiguous 16B-aligned nontemporal v4f stream.

__global__ __launch_bounds__(256, 2)
void wigner_fused_kernel(const float* __restrict__ xyz, float* __restrict__ out, int Ntot) {
    __shared__ float img[32 * 625];

    const int t = threadIdx.x;
    const int gp = blockIdx.x * 256 + t;

    float x = 0.0f, y = 0.0f, z = 1.0f;
    if (gp < Ntot) {
        x = xyz[3 * gp + 0];
        y = xyz[3 * gp + 1];
        z = xyz[3 * gp + 2];
    }

    // trig without trig: ct = vz (clipped), st = sqrt(1-ct^2), cp/sp from x,y
    const float r2 = x * x + y * y + z * z;
    const float rinv = rsqrtf(fmaxf(r2, 1e-24f));
    const float ct = fminf(fmaxf(z * rinv, -1.0f), 1.0f);
    const float st = sqrtf(fmaxf(1.0f - ct * ct, 0.0f));
    const float rxy2 = x * x + y * y;
    float cp = 1.0f, sp = 0.0f;
    if (rxy2 > 0.0f) {
        const float ri = rsqrtf(rxy2);
        cp = x * ri;
        sp = y * ri;
    }
    // only ct, st, cp, sp stay live across the chunk loop (4 VGPRs)

    // zero whole image once (zero-structure slots never rewritten)
    v4f* b4 = (v4f*)img;
    const v4f z4 = {0.0f, 0.0f, 0.0f, 0.0f};
#pragma unroll 4
    for (int k = t; k < 5000; k += 256) b4[k] = z4;
    __syncthreads();

    const int p0 = t & 31;
    const long long blk_f = (long long)blockIdx.x * 256 * 625;

    for (int c = 0; c < 8; ++c) {
        const int base_pt = blockIdx.x * 256 + c * 32;
        if (base_pt >= Ntot) break;  // uniform across block
        const int vp = min(32, Ntot - base_pt);

        // scatter: owning 32 threads recompute D and stream into the image
        if ((t >> 5) == c && gp < Ntot) {
            float* __restrict__ row = img + p0 * 625;
            row[0] = 1.0f;  // l=0 block

            // R1 in real-SH l=1 basis order (y,z,x), row-major 3x3
            float D1[9] = {cp,      0.0f, -sp,
                           st * sp, ct,   st * cp,
                           ct * sp, -st,  ct * cp};
            write_l1(D1, row, std::make_index_sequence<9>{});

            float D2[25];
            level<T2, 2, true>(D1, D1, D2, row, std::make_index_sequence<25>{});
            float D3[49];
            level<T3, 3, true>(D1, D2, D3, row, std::make_index_sequence<49>{});
            level<T4, 4, false>(D1, D3, nullptr, row, std::make_index_sequence<81>{});
        }
        __syncthreads();

        const long long out_f = blk_f + (long long)c * 32 * 625;
        if (vp == 32) {
            const v4f* src = (const v4f*)img;
            v4f* dst = (v4f*)(out + out_f);
#pragma unroll 4
            for (int k = t; k < 5000; k += 256) {
                __builtin_nontemporal_store(src[k], dst + k);
            }
        } else {
            const int vf = vp * 625;
            for (int k = t; k < vf; k += 256) {
                out[out_f + k] = img[k];
            }
        }
        __syncthreads();
    }
}

extern "C" void kernel_launch(void* const* d_in, const int* in_sizes, int n_in,
                              void* d_out, int out_size, void* d_ws, size_t ws_size,
                              hipStream_t stream) {
    const float* xyz = (const float*)d_in[0];
    float* out = (float*)d_out;
    const int N = in_sizes[0] / 3;
    const int blocks = (N + 255) / 256;
    hipLaunchKernelGGL(wigner_fused_kernel, dim3(blocks), dim3(256), 0, stream,
                       xyz, out, N);
}